// Round 8
// baseline (524.474 us; speedup 1.0000x reference)
//
#include <hip/hip_runtime.h>

typedef _Float16 f16;
typedef f16 f16x2 __attribute__((ext_vector_type(2)));
typedef f16 f16x4 __attribute__((ext_vector_type(4)));
typedef f16 f16x8 __attribute__((ext_vector_type(8)));
typedef float f32x4 __attribute__((ext_vector_type(4)));
typedef int i32x4 __attribute__((ext_vector_type(4)));
typedef __fp16 fp16x2_raw __attribute__((ext_vector_type(2)));

#define MT 64
#define NSTEP 30
#define LOG2E 1.4426950408889634f

__device__ __forceinline__ float rcp_f(float x) { return __builtin_amdgcn_rcpf(x); }
__device__ __forceinline__ float exp2_f(float x) {
#if __has_builtin(__builtin_amdgcn_exp2f)
    return __builtin_amdgcn_exp2f(x);
#else
    return __builtin_exp2f(x);
#endif
}
__device__ __forceinline__ int pk2i(float a, float b) {
    fp16x2_raw t = __builtin_amdgcn_cvt_pkrtz(a, b);
    return __builtin_bit_cast(int, t);
}
__device__ __forceinline__ f16x4 pk4(float a, float b, float c, float d) {
    int lo = pk2i(a, b), hi = pk2i(c, d);
    int2 t = {lo, hi};
    return __builtin_bit_cast(f16x4, t);
}

// One WG = 64 batch rows, 8 waves; wave wv owns hidden units [16wv,16wv+16).
// Transposed GEMMs: D = W(A) @ h(B); D-layout col=lane&15, row=(lane>>4)*4+r.
// PREFOLD: x(t) = leaky(M1*h(t-1) + b_u), M1 = W_emb@W_pos (16x128): x-path
// is a GEMM on h(t-1) fused into the gates' kf loop. ONE barrier per step.
// x D-tile -> B-frag via 4 __shfl. pred(t-1) emitted fire-and-forget.
// Gates pre-scaled by -log2e / +2log2e -> v_exp_f32 directly; gate bias
// rides k-slot 16 of wih (xf[g==2][0] = 1.0).
// R8: wu/wp/b_u/b_pos re-read from LDS every step via ONE asm-perturbed
// zero (pz) folded into recomputed addresses (LDS bases fold into ds_read
// imm). R7's four separate perturbed offsets cost 4 live VGPRs -> demand
// ~131 -> allocator capped at 128, residual spill (FETCH 52MB, WRITE 279MB).
// Plain __launch_bounds__(512): R4's (512,4) forced 64 VGPR -> 4.3GB spill.
__global__ __launch_bounds__(512) void mdlstm_kernel(
    const float* __restrict__ lor,   // last_obs_rel (B,2)
    const float* __restrict__ h0,    // (B,128)
    const float* __restrict__ c0,    // (B,128)
    const float* __restrict__ W_ih,  // (512,16)
    const float* __restrict__ W_hh,  // (512,128)
    const float* __restrict__ b_ih, const float* __restrict__ b_hh,
    const float* __restrict__ W_emb, // (16,12)
    const float* __restrict__ b_emb, // (16)
    const float* __restrict__ W_pos, // (12,128)
    const float* __restrict__ b_pos, // (12)
    const float* __restrict__ W_conf,// (6,128)
    const float* __restrict__ b_conf,// (6)
    float* __restrict__ out, int batch)
{
    __shared__ f16 h_lds[2 * MT * 128];   // 32 KB double-buffered
    __shared__ f16 wpos_lds[4 * 64 * 8];  // 4 KB: W_pos frags [kf][lane][8]
    __shared__ f16 weu_lds[4 * 64 * 8];   // 4 KB: M1 frags   [kf][lane][8]
    __shared__ f16 x0_lds[MT * 16];       // 2 KB: x(0) [batch row][emb]
    __shared__ float bu_lds[16];          // b_u[e] = W_emb@b_pos + b_emb
    __shared__ float bp_lds[16];          // b_pos padded to 16

    char* hb  = (char*)h_lds;
    char* wpb = (char*)wpos_lds;
    char* wub = (char*)weu_lds;
    char* x0b = (char*)x0_lds;
    char* bub = (char*)bu_lds;
    char* bpb = (char*)bp_lds;

    const int tid = threadIdx.x;
    const int wv  = tid >> 6;
    const int ln  = tid & 63;
    const int g   = ln >> 4;
    const int q   = ln & 15;
    const int b0  = blockIdx.x * MT;
    if (b0 >= batch) return;

    const float gsc[4] = {-LOG2E, -LOG2E, 2.f * LOG2E, -LOG2E};

    // ---- persistent weight fragments ----
    f16x8 whh[4][4];
    #pragma unroll
    for (int g4 = 0; g4 < 4; ++g4) {
        const int col = g4 * 128 + wv * 16 + q;
        #pragma unroll
        for (int kf = 0; kf < 4; ++kf) {
            const float* p = W_hh + col * 128 + kf * 32 + g * 8;
            f16x8 v;
            #pragma unroll
            for (int j = 0; j < 8; ++j) v[j] = (f16)(p[j] * gsc[g4]);
            whh[g4][kf] = v;
        }
    }
    f16x8 wih[4];                // K=16 x + bias at k=16 (g==2,j==0)
    #pragma unroll
    for (int g4 = 0; g4 < 4; ++g4) {
        const int col = g4 * 128 + wv * 16 + q;
        f16x8 v = {};
        if (g < 2) {
            const float* p = W_ih + col * 16 + g * 8;
            #pragma unroll
            for (int j = 0; j < 8; ++j) v[j] = (f16)(p[j] * gsc[g4]);
        } else if (g == 2) {
            v[0] = (f16)((b_ih[col] + b_hh[col]) * gsc[g4]);
        }
        wih[g4] = v;
    }

    // b_u / b_pos -> LDS (16 threads)
    if (tid < 16) {
        float s = b_emb[tid];
        #pragma unroll
        for (int p = 0; p < 12; ++p) s += W_emb[tid * 12 + p] * b_pos[p];
        bu_lds[tid] = s;
        bp_lds[tid] = (tid < 12) ? b_pos[tid] : 0.f;
    }

    // W_pos + M1 fragments -> LDS (wave 0)
    if (wv == 0) {
        #pragma unroll
        for (int kf = 0; kf < 4; ++kf) {
            f16x8 v = {};
            if (q < 12) {
                const float* p = W_pos + q * 128 + kf * 32 + g * 8;
                #pragma unroll
                for (int j = 0; j < 8; ++j) v[j] = (f16)p[j];
            }
            *(f16x8*)(wpb + kf * 1024 + ln * 16) = v;
        }
        float we_q[12];
        #pragma unroll
        for (int p = 0; p < 12; ++p) we_q[p] = W_emb[q * 12 + p];
        #pragma unroll
        for (int kf = 0; kf < 4; ++kf) {
            f16x8 v;
            #pragma unroll
            for (int j = 0; j < 8; ++j) {
                const int k = kf * 32 + g * 8 + j;
                float s = 0.f;
                #pragma unroll
                for (int p = 0; p < 12; ++p) s += we_q[p] * W_pos[p * 128 + k];
                v[j] = (f16)s;
            }
            *(f16x8*)(wub + kf * 1024 + ln * 16) = v;
        }
    }

    // ---- c state: c[16mt+q][16wv+4g..+3] ----
    f32x4 c_st[4];
    #pragma unroll
    for (int mt = 0; mt < 4; ++mt)
        c_st[mt] = *(const f32x4*)(c0 + (size_t)(b0 + 16 * mt + q) * 128 + 16 * wv + 4 * g);

    // ---- loop-invariant LDS byte addresses ----
    const int swz = (q & 7) << 5;
    int rdbase[4];
    #pragma unroll
    for (int kf = 0; kf < 4; ++kf) rdbase[kf] = q * 256 + ((kf * 64 + g * 16) ^ swz);
    const int wrb = q * 256 + ((wv * 32 + g * 8) ^ swz);
    const int src0 = ((g & 1) << 5) | q;   // x-shuffle sources (valid g<2)
    const int src1 = src0 + 16;

    // single perturbed zero: re-"modified" each step so the LDS-resident
    // weight/bias loads can't be promoted to persistent registers
    int pz = 0;

    float* outp = out + (size_t)(b0 + 16 * wv + q) * 360 + 2 * g * 60; // wv<4,g<3

    // ---- stage h0 -> buf0 ----
    {
        const int row = tid >> 3, seg = tid & 7;
        const float* p = h0 + (size_t)(b0 + row) * 128 + seg * 16;
        const int rswz = (row & 7) << 5;
        #pragma unroll
        for (int hh2 = 0; hh2 < 2; ++hh2) {
            f16x8 v;
            #pragma unroll
            for (int j = 0; j < 8; ++j) v[j] = (f16)p[hh2 * 8 + j];
            const int off = row * 256 + (((seg * 4 + 2 * hh2) * 8) ^ rswz);
            *(f16x8*)(hb + off) = v;
        }
    }

    // ---- x(0) = leaky(W_emb@rel0^T + b_emb) -> x0_lds: waves 0-3, mt=wv ----
    if (wv < 4) {
        f16x8 wemb = {};             // A[emb q][traj k], k<12
        #pragma unroll
        for (int j = 0; j < 8; ++j) {
            const int k = g * 8 + j;
            if (k < 12) wemb[j] = (f16)W_emb[q * 12 + k];
        }
        const float2 xy = *(const float2*)(lor + (size_t)(b0 + 16 * wv + q) * 2);
        f16x8 rf = {};
        if (g < 2) {
            #pragma unroll
            for (int j = 0; j < 8; ++j) {
                const int k = g * 8 + j;
                if (k < 12) rf[j] = (f16)((k & 1) ? xy.y : xy.x);
            }
        }
        f32x4 u0;
        #pragma unroll
        for (int r = 0; r < 4; ++r) u0[r] = b_emb[4 * g + r];
        u0 = __builtin_amdgcn_mfma_f32_16x16x32_f16(wemb, rf, u0, 0, 0, 0);
        *(f16x4*)(x0b + (16 * wv + q) * 32 + g * 8) =
            pk4(fmaxf(u0[0], .01f * u0[0]), fmaxf(u0[1], .01f * u0[1]),
                fmaxf(u0[2], .01f * u0[2]), fmaxf(u0[3], .01f * u0[3]));
    }

    // ---- conf = softmax(h0 @ W_conf^T + b_conf) ----
    {
        const int e  = tid >> 3;
        const int p8 = tid & 7;
        const float* hp = h0 + (size_t)(b0 + e) * 128 + p8 * 16;
        float pc[6];
        #pragma unroll
        for (int md = 0; md < 6; ++md) {
            const float* wc = W_conf + md * 128 + p8 * 16;
            float s = 0.f;
            #pragma unroll
            for (int i = 0; i < 16; ++i) s += hp[i] * wc[i];
            pc[md] = s;
        }
        #pragma unroll
        for (int md = 0; md < 6; ++md) {
            pc[md] += __shfl_down(pc[md], 4, 8);
            pc[md] += __shfl_down(pc[md], 2, 8);
            pc[md] += __shfl_down(pc[md], 1, 8);
        }
        if (p8 == 0) {
            float mx = -1e30f;
            #pragma unroll
            for (int md = 0; md < 6; ++md) { pc[md] += b_conf[md]; mx = fmaxf(mx, pc[md]); }
            float s = 0.f;
            #pragma unroll
            for (int md = 0; md < 6; ++md) { pc[md] = __expf(pc[md] - mx); s += pc[md]; }
            const float rs = rcp_f(s);
            float* cp = out + (size_t)batch * 360 + (size_t)(b0 + e) * 6;
            #pragma unroll
            for (int md = 0; md < 6; ++md) cp[md] = pc[md] * rs;
        }
    }

    __syncthreads();

#define STEP(BR, BW, T_, FIRST) do {                                            \
    asm volatile("" : "+v"(pz));                                                \
    const int wuoff = ln * 16 + pz;      /* shared by wub & wpb reads */        \
    const int boff  = g * 16 + pz;       /* shared by bub & bpb reads */        \
    _Pragma("unroll")                                                           \
    for (int mt = 0; mt < 4; ++mt) {                                            \
        f32x4 a0 = {0,0,0,0}, a1 = {0,0,0,0}, a2 = {0,0,0,0}, a3 = {0,0,0,0};   \
        f32x4 uacc;                                                             \
        if (FIRST) uacc = a0;                                                   \
        else       uacc = *(const f32x4*)(bub + boff);                          \
        _Pragma("unroll")                                                       \
        for (int kf = 0; kf < 4; ++kf) {                                        \
            f16x8 hf = *(const f16x8*)(hb + (BR) + mt * 4096 + rdbase[kf]);     \
            a0 = __builtin_amdgcn_mfma_f32_16x16x32_f16(whh[0][kf], hf, a0, 0, 0, 0); \
            a1 = __builtin_amdgcn_mfma_f32_16x16x32_f16(whh[1][kf], hf, a1, 0, 0, 0); \
            a2 = __builtin_amdgcn_mfma_f32_16x16x32_f16(whh[2][kf], hf, a2, 0, 0, 0); \
            a3 = __builtin_amdgcn_mfma_f32_16x16x32_f16(whh[3][kf], hf, a3, 0, 0, 0); \
            if (!(FIRST)) {                                                     \
                f16x8 wu = *(const f16x8*)(wub + wuoff + kf * 1024);            \
                uacc = __builtin_amdgcn_mfma_f32_16x16x32_f16(wu, hf, uacc, 0, 0, 0); \
            }                                                                   \
        }                                                                       \
        f16x8 xf;                                                               \
        if (FIRST) {                                                            \
            i32x4 xw = {0, 0, 0, 0};                                            \
            if (g < 2)       xw = *(const i32x4*)(x0b + (mt * 16 + q) * 32 + g * 16); \
            else if (g == 2) xw[0] = 0x3C00;                                    \
            xf = __builtin_bit_cast(f16x8, xw);                                 \
        } else {                                                                \
            const int d0i = pk2i(fmaxf(uacc[0], .01f * uacc[0]), fmaxf(uacc[1], .01f * uacc[1])); \
            const int d1i = pk2i(fmaxf(uacc[2], .01f * uacc[2]), fmaxf(uacc[3], .01f * uacc[3])); \
            i32x4 xw;                                                           \
            xw[0] = __shfl(d0i, src0, 64);                                      \
            xw[1] = __shfl(d1i, src0, 64);                                      \
            xw[2] = __shfl(d0i, src1, 64);                                      \
            xw[3] = __shfl(d1i, src1, 64);                                      \
            if (g == 2)      { xw[0] = 0x3C00; xw[1] = 0; xw[2] = 0; xw[3] = 0; } \
            else if (g == 3) { xw[0] = 0; xw[1] = 0; xw[2] = 0; xw[3] = 0; }    \
            xf = __builtin_bit_cast(f16x8, xw);                                 \
        }                                                                       \
        a0 = __builtin_amdgcn_mfma_f32_16x16x32_f16(wih[0], xf, a0, 0, 0, 0);   \
        a1 = __builtin_amdgcn_mfma_f32_16x16x32_f16(wih[1], xf, a1, 0, 0, 0);   \
        a2 = __builtin_amdgcn_mfma_f32_16x16x32_f16(wih[2], xf, a2, 0, 0, 0);   \
        a3 = __builtin_amdgcn_mfma_f32_16x16x32_f16(wih[3], xf, a3, 0, 0, 0);   \
        f32x4 hv;                                                               \
        _Pragma("unroll")                                                       \
        for (int r = 0; r < 4; ++r) {                                           \
            const float ei = exp2_f(a0[r]);                                     \
            const float ef = exp2_f(a1[r]);                                     \
            const float eg = exp2_f(a2[r]);                                     \
            const float eo = exp2_f(a3[r]);                                     \
            const float pi = 1.f + ei, pf = 1.f + ef, pg = 1.f + eg;            \
            const float t1 = pi * pg;                                           \
            const float R1 = rcp_f(t1 * pf);                                    \
            const float sf = t1 * R1;                                           \
            const float itg = (eg - 1.f) * (pf * R1);                           \
            const float cv = sf * c_st[mt][r] + itg;                            \
            c_st[mt][r] = cv;                                                   \
            const float ec = exp2_f(fminf(cv, 30.f) * (2.f * LOG2E));           \
            const float R2 = rcp_f((1.f + eo) * (1.f + ec));                    \
            hv[r] = (ec - 1.f) * R2;                                            \
        }                                                                       \
        *(f16x4*)(hb + (BW) + mt * 4096 + wrb) = pk4(hv[0], hv[1], hv[2], hv[3]); \
    }                                                                           \
    if (!(FIRST) && wv < 4) {   /* pred(T_-1) from read buffer, fire&forget */  \
        f32x4 racc = *(const f32x4*)(bpb + boff);                               \
        _Pragma("unroll")                                                       \
        for (int kf = 0; kf < 4; ++kf) {                                        \
            f16x8 wp = *(const f16x8*)(wpb + wuoff + kf * 1024);                \
            f16x8 hf = *(const f16x8*)(hb + (BR) + wv * 4096 + rdbase[kf]);     \
            racc = __builtin_amdgcn_mfma_f32_16x16x32_f16(wp, hf, racc, 0, 0, 0); \
        }                                                                       \
        if (g < 3) {                                                            \
            float2 s0 = {racc[0], racc[1]};                                     \
            float2 s1 = {racc[2], racc[3]};                                     \
            float* pp = outp + 2 * ((T_) - 1);                                  \
            *(float2*)pp = s0;                                                  \
            *(float2*)(pp + 60) = s1;                                           \
        }                                                                       \
    }                                                                           \
    __syncthreads();                                                            \
} while (0)

    STEP(0, 16384, 0, true);          // t=0: x from x0_lds, no pred yet
    #pragma unroll 1
    for (int tt = 1; tt < NSTEP - 1; tt += 2) {
        STEP(16384, 0, tt, false);    // emits pred(tt-1)
        STEP(0, 16384, tt + 1, false);
    }
    STEP(16384, 0, NSTEP - 1, false); // t=29, emits pred(28); h(29) -> buf0

    if (wv < 4) {                     // epilogue: pred(29) from buf0
        asm volatile("" : "+v"(pz));
        const int wuoff = ln * 16 + pz;
        const int boff  = g * 16 + pz;
        f32x4 racc = *(const f32x4*)(bpb + boff);
        #pragma unroll
        for (int kf = 0; kf < 4; ++kf) {
            f16x8 wp = *(const f16x8*)(wpb + wuoff + kf * 1024);
            f16x8 hf = *(const f16x8*)(hb + wv * 4096 + rdbase[kf]);
            racc = __builtin_amdgcn_mfma_f32_16x16x32_f16(wp, hf, racc, 0, 0, 0);
        }
        if (g < 3) {
            float2 s0 = {racc[0], racc[1]};
            float2 s1 = {racc[2], racc[3]};
            float* pp = outp + 2 * (NSTEP - 1);
            *(float2*)pp = s0;
            *(float2*)(pp + 60) = s1;
        }
    }
#undef STEP
}

extern "C" void kernel_launch(void* const* d_in, const int* in_sizes, int n_in,
                              void* d_out, int out_size, void* d_ws, size_t ws_size,
                              hipStream_t stream) {
    const float* last_obs_rel = (const float*)d_in[1];
    const float* h0     = (const float*)d_in[2];
    const float* c0     = (const float*)d_in[3];
    const float* W_ih   = (const float*)d_in[4];
    const float* W_hh   = (const float*)d_in[5];
    const float* b_ih   = (const float*)d_in[6];
    const float* b_hh   = (const float*)d_in[7];
    const float* W_emb  = (const float*)d_in[8];
    const float* b_emb  = (const float*)d_in[9];
    const float* W_pos  = (const float*)d_in[10];
    const float* b_pos  = (const float*)d_in[11];
    const float* W_conf = (const float*)d_in[12];
    const float* b_conf = (const float*)d_in[13];
    float* out = (float*)d_out;

    const int batch = in_sizes[1] / 2;   // last_obs_rel is (B,2)
    const int grid  = (batch + MT - 1) / MT;
    mdlstm_kernel<<<grid, 512, 0, stream>>>(last_obs_rel, h0, c0, W_ih, W_hh,
                                            b_ih, b_hh, W_emb, b_emb, W_pos,
                                            b_pos, W_conf, b_conf, out, batch);
}

// Round 9
// 477.988 us; speedup vs baseline: 1.0973x; 1.0973x over previous
//
#include <hip/hip_runtime.h>

typedef _Float16 f16;
typedef f16 f16x2 __attribute__((ext_vector_type(2)));
typedef f16 f16x4 __attribute__((ext_vector_type(4)));
typedef f16 f16x8 __attribute__((ext_vector_type(8)));
typedef float f32x4 __attribute__((ext_vector_type(4)));
typedef int i32x4 __attribute__((ext_vector_type(4)));
typedef __fp16 fp16x2_raw __attribute__((ext_vector_type(2)));

#define MT 64
#define NSTEP 30
#define LOG2E 1.4426950408889634f

__device__ __forceinline__ float rcp_f(float x) { return __builtin_amdgcn_rcpf(x); }
__device__ __forceinline__ float exp2_f(float x) {
#if __has_builtin(__builtin_amdgcn_exp2f)
    return __builtin_amdgcn_exp2f(x);
#else
    return __builtin_exp2f(x);
#endif
}
__device__ __forceinline__ int pk2i(float a, float b) {
    fp16x2_raw t = __builtin_amdgcn_cvt_pkrtz(a, b);
    return __builtin_bit_cast(int, t);
}
__device__ __forceinline__ f16x4 pk4(float a, float b, float c, float d) {
    int lo = pk2i(a, b), hi = pk2i(c, d);
    int2 t = {lo, hi};
    return __builtin_bit_cast(f16x4, t);
}

// One WG = 64 batch rows, 8 waves; wave wv owns hidden units [16wv,16wv+16).
// Transposed GEMMs: D = W(A) @ h(B); D-layout col=lane&15, row=(lane>>4)*4+r.
// TWO barriers/step (R3 register economics: 112 VGPR, no spill) but phase 2
// is now BALANCED via the prefold x(t+1)=leaky(M1*h(t)+b_u), M1=W_emb@W_pos:
//   phase 1 (all 8 waves): gates MFMA + activations + h(t) write
//   phase 2: waves 0-3 -> pred(t) GEMM (fire-and-forget to HBM)
//            waves 4-7 -> u-GEMM -> leaky -> x(t+1) into x_lds
// No serial rel->emb chain, no threadfence, no idle waves.
// R5-R8 lesson: the ONE-barrier variant needs ~132 VGPR (uacc+shuffles live
// in phase 1) -> pins at 128-cap and spills. This split keeps phase-1
// registers identical to R3.
// wp/wu/b_u/b_pos re-read from LDS every step via one asm-perturbed zero
// (pz) so LLVM can't promote them to ~24 persistent VGPRs (R7 mechanism).
// Gates pre-scaled by -log2e / +2log2e -> v_exp_f32 directly; gate bias
// rides k-slot 16 of wih (xf[g==2][0]=1.0).
// Plain __launch_bounds__(512): R4's (512,4) forced 64 VGPR -> 4.3GB spill.
__global__ __launch_bounds__(512) void mdlstm_kernel(
    const float* __restrict__ lor,   // last_obs_rel (B,2)
    const float* __restrict__ h0,    // (B,128)
    const float* __restrict__ c0,    // (B,128)
    const float* __restrict__ W_ih,  // (512,16)
    const float* __restrict__ W_hh,  // (512,128)
    const float* __restrict__ b_ih, const float* __restrict__ b_hh,
    const float* __restrict__ W_emb, // (16,12)
    const float* __restrict__ b_emb, // (16)
    const float* __restrict__ W_pos, // (12,128)
    const float* __restrict__ b_pos, // (12)
    const float* __restrict__ W_conf,// (6,128)
    const float* __restrict__ b_conf,// (6)
    float* __restrict__ out, int batch)
{
    __shared__ f16 h_lds[2 * MT * 128];   // 32 KB double-buffered
    __shared__ f16 wpos_lds[4 * 64 * 8];  // 4 KB: W_pos frags [kf][lane][8]
    __shared__ f16 weu_lds[4 * 64 * 8];   // 4 KB: M1 frags   [kf][lane][8]
    __shared__ f16 x_lds[MT * 16];        // 2 KB: x(t) [batch row][emb]
    __shared__ float bu_lds[16];          // b_u[e] = W_emb@b_pos + b_emb
    __shared__ float bp_lds[16];          // b_pos padded to 16

    char* hb  = (char*)h_lds;
    char* wpb = (char*)wpos_lds;
    char* wub = (char*)weu_lds;
    char* xb  = (char*)x_lds;
    char* bub = (char*)bu_lds;
    char* bpb = (char*)bp_lds;

    const int tid = threadIdx.x;
    const int wv  = tid >> 6;
    const int ln  = tid & 63;
    const int g   = ln >> 4;
    const int q   = ln & 15;
    const int b0  = blockIdx.x * MT;
    if (b0 >= batch) return;

    const float gsc[4] = {-LOG2E, -LOG2E, 2.f * LOG2E, -LOG2E};

    // ---- persistent weight fragments ----
    f16x8 whh[4][4];
    #pragma unroll
    for (int g4 = 0; g4 < 4; ++g4) {
        const int col = g4 * 128 + wv * 16 + q;
        #pragma unroll
        for (int kf = 0; kf < 4; ++kf) {
            const float* p = W_hh + col * 128 + kf * 32 + g * 8;
            f16x8 v;
            #pragma unroll
            for (int j = 0; j < 8; ++j) v[j] = (f16)(p[j] * gsc[g4]);
            whh[g4][kf] = v;
        }
    }
    f16x8 wih[4];                // K=16 x + bias at k=16 (g==2,j==0)
    #pragma unroll
    for (int g4 = 0; g4 < 4; ++g4) {
        const int col = g4 * 128 + wv * 16 + q;
        f16x8 v = {};
        if (g < 2) {
            const float* p = W_ih + col * 16 + g * 8;
            #pragma unroll
            for (int j = 0; j < 8; ++j) v[j] = (f16)(p[j] * gsc[g4]);
        } else if (g == 2) {
            v[0] = (f16)((b_ih[col] + b_hh[col]) * gsc[g4]);
        }
        wih[g4] = v;
    }

    // b_u / b_pos -> LDS (16 threads)
    if (tid < 16) {
        float s = b_emb[tid];
        #pragma unroll
        for (int p = 0; p < 12; ++p) s += W_emb[tid * 12 + p] * b_pos[p];
        bu_lds[tid] = s;
        bp_lds[tid] = (tid < 12) ? b_pos[tid] : 0.f;
    }

    // W_pos + M1 fragments -> LDS (wave 0)
    if (wv == 0) {
        #pragma unroll
        for (int kf = 0; kf < 4; ++kf) {
            f16x8 v = {};
            if (q < 12) {
                const float* p = W_pos + q * 128 + kf * 32 + g * 8;
                #pragma unroll
                for (int j = 0; j < 8; ++j) v[j] = (f16)p[j];
            }
            *(f16x8*)(wpb + kf * 1024 + ln * 16) = v;
        }
        float we_q[12];
        #pragma unroll
        for (int p = 0; p < 12; ++p) we_q[p] = W_emb[q * 12 + p];
        #pragma unroll
        for (int kf = 0; kf < 4; ++kf) {
            f16x8 v;
            #pragma unroll
            for (int j = 0; j < 8; ++j) {
                const int k = kf * 32 + g * 8 + j;
                float s = 0.f;
                #pragma unroll
                for (int p = 0; p < 12; ++p) s += we_q[p] * W_pos[p * 128 + k];
                v[j] = (f16)s;
            }
            *(f16x8*)(wub + kf * 1024 + ln * 16) = v;
        }
    }

    // ---- c state: c[16mt+q][16wv+4g..+3] ----
    f32x4 c_st[4];
    #pragma unroll
    for (int mt = 0; mt < 4; ++mt)
        c_st[mt] = *(const f32x4*)(c0 + (size_t)(b0 + 16 * mt + q) * 128 + 16 * wv + 4 * g);

    // ---- loop-invariant LDS byte addresses ----
    const int swz = (q & 7) << 5;
    int rdbase[4];
    #pragma unroll
    for (int kf = 0; kf < 4; ++kf) rdbase[kf] = q * 256 + ((kf * 64 + g * 16) ^ swz);
    const int wrb = q * 256 + ((wv * 32 + g * 8) ^ swz);
    const int xrd = q * 32 + g * 16;     // phase-1 x read (valid g<2)

    // single perturbed zero: re-"modified" each step so the LDS-resident
    // weight/bias loads can't be promoted to persistent registers
    int pz = 0;

    float* outp = out + (size_t)(b0 + 16 * wv + q) * 360 + 2 * g * 60; // wv<4,g<3

    // ---- stage h0 -> buf0 ----
    {
        const int row = tid >> 3, seg = tid & 7;
        const float* p = h0 + (size_t)(b0 + row) * 128 + seg * 16;
        const int rswz = (row & 7) << 5;
        #pragma unroll
        for (int hh2 = 0; hh2 < 2; ++hh2) {
            f16x8 v;
            #pragma unroll
            for (int j = 0; j < 8; ++j) v[j] = (f16)p[hh2 * 8 + j];
            const int off = row * 256 + (((seg * 4 + 2 * hh2) * 8) ^ rswz);
            *(f16x8*)(hb + off) = v;
        }
    }

    // ---- x(0) = leaky(W_emb@rel0^T + b_emb) -> x_lds: waves 0-3, mt=wv ----
    if (wv < 4) {
        f16x8 wemb = {};             // A[emb q][traj k], k<12
        #pragma unroll
        for (int j = 0; j < 8; ++j) {
            const int k = g * 8 + j;
            if (k < 12) wemb[j] = (f16)W_emb[q * 12 + k];
        }
        const float2 xy = *(const float2*)(lor + (size_t)(b0 + 16 * wv + q) * 2);
        f16x8 rf = {};
        if (g < 2) {
            #pragma unroll
            for (int j = 0; j < 8; ++j) {
                const int k = g * 8 + j;
                if (k < 12) rf[j] = (f16)((k & 1) ? xy.y : xy.x);
            }
        }
        f32x4 u0;
        #pragma unroll
        for (int r = 0; r < 4; ++r) u0[r] = b_emb[4 * g + r];
        u0 = __builtin_amdgcn_mfma_f32_16x16x32_f16(wemb, rf, u0, 0, 0, 0);
        *(f16x4*)(xb + (16 * wv + q) * 32 + g * 8) =
            pk4(fmaxf(u0[0], .01f * u0[0]), fmaxf(u0[1], .01f * u0[1]),
                fmaxf(u0[2], .01f * u0[2]), fmaxf(u0[3], .01f * u0[3]));
    }

    // ---- conf = softmax(h0 @ W_conf^T + b_conf) ----
    {
        const int e  = tid >> 3;
        const int p8 = tid & 7;
        const float* hp = h0 + (size_t)(b0 + e) * 128 + p8 * 16;
        float pc[6];
        #pragma unroll
        for (int md = 0; md < 6; ++md) {
            const float* wc = W_conf + md * 128 + p8 * 16;
            float s = 0.f;
            #pragma unroll
            for (int i = 0; i < 16; ++i) s += hp[i] * wc[i];
            pc[md] = s;
        }
        #pragma unroll
        for (int md = 0; md < 6; ++md) {
            pc[md] += __shfl_down(pc[md], 4, 8);
            pc[md] += __shfl_down(pc[md], 2, 8);
            pc[md] += __shfl_down(pc[md], 1, 8);
        }
        if (p8 == 0) {
            float mx = -1e30f;
            #pragma unroll
            for (int md = 0; md < 6; ++md) { pc[md] += b_conf[md]; mx = fmaxf(mx, pc[md]); }
            float s = 0.f;
            #pragma unroll
            for (int md = 0; md < 6; ++md) { pc[md] = __expf(pc[md] - mx); s += pc[md]; }
            const float rs = rcp_f(s);
            float* cp = out + (size_t)batch * 360 + (size_t)(b0 + e) * 6;
            #pragma unroll
            for (int md = 0; md < 6; ++md) cp[md] = pc[md] * rs;
        }
    }

    __syncthreads();

#define STEP(BR, BW, T_, LAST) do {                                             \
    asm volatile("" : "+v"(pz));                                                \
    const int wuoff = ln * 16 + pz;      /* shared by wub & wpb reads */        \
    const int boff  = g * 16 + pz;       /* shared by bub & bpb reads */        \
    /* -------- phase 1: gates + activations + h(T_) write, all waves ----- */ \
    _Pragma("unroll")                                                           \
    for (int mt = 0; mt < 4; ++mt) {                                            \
        f32x4 a0 = {0,0,0,0}, a1 = {0,0,0,0}, a2 = {0,0,0,0}, a3 = {0,0,0,0};   \
        _Pragma("unroll")                                                       \
        for (int kf = 0; kf < 4; ++kf) {                                        \
            f16x8 hf = *(const f16x8*)(hb + (BR) + mt * 4096 + rdbase[kf]);     \
            a0 = __builtin_amdgcn_mfma_f32_16x16x32_f16(whh[0][kf], hf, a0, 0, 0, 0); \
            a1 = __builtin_amdgcn_mfma_f32_16x16x32_f16(whh[1][kf], hf, a1, 0, 0, 0); \
            a2 = __builtin_amdgcn_mfma_f32_16x16x32_f16(whh[2][kf], hf, a2, 0, 0, 0); \
            a3 = __builtin_amdgcn_mfma_f32_16x16x32_f16(whh[3][kf], hf, a3, 0, 0, 0); \
        }                                                                       \
        {                                                                       \
            i32x4 xw = {0, 0, 0, 0};                                            \
            if (g < 2)       xw = *(const i32x4*)(xb + mt * 512 + xrd);         \
            else if (g == 2) xw[0] = 0x3C00;                                    \
            const f16x8 xf = __builtin_bit_cast(f16x8, xw);                     \
            a0 = __builtin_amdgcn_mfma_f32_16x16x32_f16(wih[0], xf, a0, 0, 0, 0); \
            a1 = __builtin_amdgcn_mfma_f32_16x16x32_f16(wih[1], xf, a1, 0, 0, 0); \
            a2 = __builtin_amdgcn_mfma_f32_16x16x32_f16(wih[2], xf, a2, 0, 0, 0); \
            a3 = __builtin_amdgcn_mfma_f32_16x16x32_f16(wih[3], xf, a3, 0, 0, 0); \
        }                                                                       \
        f32x4 hv;                                                               \
        _Pragma("unroll")                                                       \
        for (int r = 0; r < 4; ++r) {                                           \
            const float ei = exp2_f(a0[r]);                                     \
            const float ef = exp2_f(a1[r]);                                     \
            const float eg = exp2_f(a2[r]);                                     \
            const float eo = exp2_f(a3[r]);                                     \
            const float pi = 1.f + ei, pf = 1.f + ef, pg = 1.f + eg;            \
            const float t1 = pi * pg;                                           \
            const float R1 = rcp_f(t1 * pf);                                    \
            const float sf = t1 * R1;                                           \
            const float itg = (eg - 1.f) * (pf * R1);                           \
            const float cv = sf * c_st[mt][r] + itg;                            \
            c_st[mt][r] = cv;                                                   \
            const float ec = exp2_f(fminf(cv, 30.f) * (2.f * LOG2E));           \
            const float R2 = rcp_f((1.f + eo) * (1.f + ec));                    \
            hv[r] = (ec - 1.f) * R2;                                            \
        }                                                                       \
        *(f16x4*)(hb + (BW) + mt * 4096 + wrb) = pk4(hv[0], hv[1], hv[2], hv[3]); \
    }                                                                           \
    __syncthreads();  /* h(T_) ready */                                         \
    /* -------- phase 2: split -- waves 0-3 pred(T_), waves 4-7 x(T_+1) --- */ \
    if (wv < 4) {                                                               \
        f32x4 racc = *(const f32x4*)(bpb + boff);                               \
        _Pragma("unroll")                                                       \
        for (int kf = 0; kf < 4; ++kf) {                                        \
            f16x8 wp = *(const f16x8*)(wpb + wuoff + kf * 1024);                \
            f16x8 hf = *(const f16x8*)(hb + (BW) + wv * 4096 + rdbase[kf]);     \
            racc = __builtin_amdgcn_mfma_f32_16x16x32_f16(wp, hf, racc, 0, 0, 0); \
        }                                                                       \
        if (g < 3) {                                                            \
            float2 s0 = {racc[0], racc[1]};                                     \
            float2 s1 = {racc[2], racc[3]};                                     \
            float* pp = outp + 2 * (T_);                                        \
            *(float2*)pp = s0;                                                  \
            *(float2*)(pp + 60) = s1;                                           \
        }                                                                       \
    } else if (!(LAST)) {                                                       \
        const int mt = wv - 4;                                                  \
        f32x4 uacc = *(const f32x4*)(bub + boff);                               \
        _Pragma("unroll")                                                       \
        for (int kf = 0; kf < 4; ++kf) {                                        \
            f16x8 wu = *(const f16x8*)(wub + wuoff + kf * 1024);                \
            f16x8 hf = *(const f16x8*)(hb + (BW) + mt * 4096 + rdbase[kf]);     \
            uacc = __builtin_amdgcn_mfma_f32_16x16x32_f16(wu, hf, uacc, 0, 0, 0); \
        }                                                                       \
        *(f16x4*)(xb + (16 * mt + q) * 32 + g * 8) =                            \
            pk4(fmaxf(uacc[0], .01f * uacc[0]), fmaxf(uacc[1], .01f * uacc[1]), \
                fmaxf(uacc[2], .01f * uacc[2]), fmaxf(uacc[3], .01f * uacc[3])); \
    }                                                                           \
    __syncthreads();  /* x(T_+1) ready; h buffers free to swap */               \
} while (0)

    #pragma unroll 1
    for (int tt = 0; tt < NSTEP; tt += 2) {
        STEP(0, 16384, tt, false);
        STEP(16384, 0, tt + 1, (tt + 1 == NSTEP - 1));
    }
#undef STEP
}

extern "C" void kernel_launch(void* const* d_in, const int* in_sizes, int n_in,
                              void* d_out, int out_size, void* d_ws, size_t ws_size,
                              hipStream_t stream) {
    const float* last_obs_rel = (const float*)d_in[1];
    const float* h0     = (const float*)d_in[2];
    const float* c0     = (const float*)d_in[3];
    const float* W_ih   = (const float*)d_in[4];
    const float* W_hh   = (const float*)d_in[5];
    const float* b_ih   = (const float*)d_in[6];
    const float* b_hh   = (const float*)d_in[7];
    const float* W_emb  = (const float*)d_in[8];
    const float* b_emb  = (const float*)d_in[9];
    const float* W_pos  = (const float*)d_in[10];
    const float* b_pos  = (const float*)d_in[11];
    const float* W_conf = (const float*)d_in[12];
    const float* b_conf = (const float*)d_in[13];
    float* out = (float*)d_out;

    const int batch = in_sizes[1] / 2;   // last_obs_rel is (B,2)
    const int grid  = (batch + MT - 1) / MT;
    mdlstm_kernel<<<grid, 512, 0, stream>>>(last_obs_rel, h0, c0, W_ih, W_hh,
                                            b_ih, b_hh, W_emb, b_emb, W_pos,
                                            b_pos, W_conf, b_conf, out, batch);
}